// Round 8
// baseline (215.991 us; speedup 1.0000x reference)
//
#include <hip/hip_runtime.h>
#include <hip/hip_bf16.h>

#define N_NODES 20000
#define N_EDGES 150000
#define D 512
#define KK 2048          // GEMM K: 3 rel slots + 1 self slot (all in tiled A)
#define KREL 1536
#define NROWS 20480
#define NTILES_M 160     // 128-row M tiles

// Tiled operand layout (MFMA-fragment order):
//   element (r, k) lives at  tile = (r>>4)*(K/32) + (k>>5)
//                            off  = (((k>>3)&3)*16 + (r&15))*8 + (k&7)
// so a wave's 16x32 fragment load is 64 lanes x 16B contiguous (1KB tile).
// A: K=2048 -> 64 tiles/row-group.  Bt: K=3072 -> 96 tiles/col-group.

typedef __attribute__((ext_vector_type(8))) short bf16x8_t;
typedef __attribute__((ext_vector_type(4))) float f32x4_t;

// ---- helpers ----
__device__ __forceinline__ unsigned short f2bf(float x) {
    unsigned u = __float_as_uint(x);
    unsigned r = u + 0x7fffu + ((u >> 16) & 1u);   // RNE
    return (unsigned short)(r >> 16);
}
__device__ __forceinline__ unsigned pack2(float a, float b) {
    return (unsigned)f2bf(a) | ((unsigned)f2bf(b) << 16);
}
__device__ __forceinline__ float bflo(unsigned u) { return __uint_as_float(u << 16); }
__device__ __forceinline__ float bfhi(unsigned u) { return __uint_as_float(u & 0xffff0000u); }

// ---- fused prep: transpose_B (384 blocks) | conv_x (5000) | count (587) ----
#define TB_BLOCKS 384
#define CX_BLOCKS 5000
#define CNT_BLOCKS 587
__global__ __launch_bounds__(256) void fused_prep(
    const float* __restrict__ W_rel, const float* __restrict__ W_self,
    short* __restrict__ Bt,
    const float* __restrict__ x, short* __restrict__ xb,
    const int* __restrict__ edst, int* __restrict__ hist,
    const int* __restrict__ ntype, int* __restrict__ tcnt) {
    __shared__ float tile[64][65];
    const int b = blockIdx.x;
    if (b < TB_BLOCKS) {
        const int z = b >> 6;                         // 0..5
        const int rem = b & 63;
        const int e0 = (rem & 7) * 64, d0 = (rem >> 3) * 64;
        const float* src = (z < 3) ? (W_rel + (size_t)z * D * D)
                                   : (W_self + (size_t)(z - 3) * D * D);
        const int cbase = (z < 3) ? z * 512 : KREL + (z - 3) * 512;
        const int tx = threadIdx.x & 63, ty = threadIdx.x >> 6;
#pragma unroll
        for (int j = 0; j < 16; ++j) {
            int dl = ty * 16 + j;
            tile[dl][tx] = src[(size_t)(d0 + dl) * D + e0 + tx];
        }
        __syncthreads();
#pragma unroll
        for (int j = 0; j < 16; ++j) {
            int e = e0 + ty * 16 + j;
            int c = cbase + d0 + tx;
            size_t addr = ((size_t)(e >> 4) * 96 + (c >> 5)) * 512
                        + (((c >> 3) & 3) * 16 + (e & 15)) * 8 + (c & 7);
            Bt[addr] = (short)f2bf(tile[tx][ty * 16 + j]);
        }
    } else if (b < TB_BLOCKS + CX_BLOCKS) {
        int idx = (b - TB_BLOCKS) * 256 + threadIdx.x;   // < 1,280,000
        const float4* s = (const float4*)x + (size_t)idx * 2;
        float4 a = s[0], bb = s[1];
        uint4 pk;
        pk.x = pack2(a.x, a.y);  pk.y = pack2(a.z, a.w);
        pk.z = pack2(bb.x, bb.y); pk.w = pack2(bb.z, bb.w);
        ((uint4*)xb)[idx] = pk;
    } else {
        int i = (b - TB_BLOCKS - CX_BLOCKS) * 256 + threadIdx.x;
        if (i < N_EDGES) atomicAdd(&hist[edst[i]], 1);
        int lane = threadIdx.x & 63;
        int t = (i < N_NODES) ? ntype[i] : 3;
        unsigned long long m0 = __ballot(t == 0), m1 = __ballot(t == 1), m2 = __ballot(t == 2);
        if (lane == 0) {
            if (m0) atomicAdd(&tcnt[0], __popcll(m0));
            if (m1) atomicAdd(&tcnt[1], __popcll(m1));
            if (m2) atomicAdd(&tcnt[2], __popcll(m2));
        }
    }
}

// ---- scan of 20000 edge-bins -> offs/cur; typeoff; rowmap padding marks ----
__global__ __launch_bounds__(1024) void scan_k(const int* __restrict__ hist,
                                               int* __restrict__ offs,
                                               int* __restrict__ cur,
                                               const int* __restrict__ tcnt,
                                               int* __restrict__ typeoff,
                                               int* __restrict__ rowmap) {
    __shared__ int part[1024];
    const int t = threadIdx.x;
    const int base = t * 20;
    int local[20];
    int sum = 0;
#pragma unroll
    for (int i = 0; i < 20; ++i) {
        int b = base + i;
        int v = (b < N_NODES) ? hist[b] : 0;
        local[i] = sum;
        sum += v;
    }
    part[t] = sum;
    __syncthreads();
    for (int off = 1; off < 1024; off <<= 1) {
        int v = part[t];
        int u = (t >= off) ? part[t - off] : 0;
        __syncthreads();
        part[t] = v + u;
        __syncthreads();
    }
    int tbase = (t > 0) ? part[t - 1] : 0;
#pragma unroll
    for (int i = 0; i < 20; ++i) {
        int b = base + i;
        if (b < N_NODES) {
            int o = tbase + local[i];
            offs[b] = o;
            cur[b] = o;
        }
    }
    if (t == 1023) offs[N_NODES] = part[1023];

    int c0 = tcnt[0], c1 = tcnt[1], c2 = tcnt[2];
    int o1 = (c0 + 127) & ~127;
    int o2 = o1 + ((c1 + 127) & ~127);
    int o3 = o2 + ((c2 + 127) & ~127);
    if (t == 0) { typeoff[0] = 0; typeoff[1] = o1; typeoff[2] = o2; typeoff[3] = o3; }
    int p0 = o1 - c0, p1 = o2 - o1 - c1, p2 = o3 - o2 - c2;
    if (t < p0) rowmap[c0 + t] = -1;
    else if (t < p0 + p1) rowmap[o1 + c1 + (t - p0)] = -1;
    else if (t - p0 - p1 < p2) rowmap[o2 + c2 + (t - p0 - p1)] = -1;
}

// ---- node->row assignment (type-grouped) + edge-id scatter (fused) ----
__global__ __launch_bounds__(256) void assign_scatter_k(
    const int* __restrict__ ntype, const int* __restrict__ typeoff,
    int* __restrict__ tcur, int* __restrict__ noderow, int* __restrict__ rowmap,
    const int* __restrict__ esrc, const int* __restrict__ edst,
    const int* __restrict__ etyp, int* __restrict__ cur, int* __restrict__ sorted) {
    int i = blockIdx.x * 256 + threadIdx.x;
    int lane = threadIdx.x & 63;
    bool valid = i < N_NODES;
    int t = valid ? ntype[i] : 3;
    unsigned long long m0 = __ballot(t == 0), m1 = __ballot(t == 1), m2 = __ballot(t == 2);
    unsigned long long below = (lane == 0) ? 0ull : (~0ull >> (64 - lane));
    int b0 = 0, b1 = 0, b2 = 0;
    if (lane == 0) {
        if (m0) b0 = atomicAdd(&tcur[0], __popcll(m0));
        if (m1) b1 = atomicAdd(&tcur[1], __popcll(m1));
        if (m2) b2 = atomicAdd(&tcur[2], __popcll(m2));
    }
    b0 = __shfl(b0, 0); b1 = __shfl(b1, 0); b2 = __shfl(b2, 0);
    if (valid) {
        unsigned long long mk = (t == 0) ? m0 : (t == 1) ? m1 : m2;
        int bs = (t == 0) ? b0 : (t == 1) ? b1 : b2;
        int row = typeoff[t] + bs + __popcll(mk & below);
        noderow[i] = row;
        rowmap[row] = i;
    }
    if (i < N_EDGES) {
        int dst = edst[i];
        int pos = atomicAdd(&cur[dst], 1);
        sorted[pos] = esrc[i] | (etyp[i] << 16);
    }
}

// ---- aggregate: one wave per dst node; writes TILED A (4 slots) ----
#define ACC_EDGE(r, v) {                                                              \
    float f0 = bflo(v.x), f1 = bfhi(v.x), f2 = bflo(v.y), f3 = bfhi(v.y);             \
    float f4 = bflo(v.z), f5 = bfhi(v.z), f6 = bflo(v.w), f7 = bfhi(v.w);             \
    if (r == 0) { a00+=f0;a01+=f1;a02+=f2;a03+=f3;a04+=f4;a05+=f5;a06+=f6;a07+=f7; k0++; } \
    else if (r == 1) { a10+=f0;a11+=f1;a12+=f2;a13+=f3;a14+=f4;a15+=f5;a16+=f6;a17+=f7; k1++; } \
    else { a20+=f0;a21+=f1;a22+=f2;a23+=f3;a24+=f4;a25+=f5;a26+=f6;a27+=f7; k2++; }   \
}
__global__ __launch_bounds__(256) void aggregate(const short* __restrict__ xb,
                                                 const int* __restrict__ offs,
                                                 const int* __restrict__ sorted,
                                                 const int* __restrict__ noderow,
                                                 short* __restrict__ A,
                                                 int* __restrict__ cnt) {
    const int wid = threadIdx.x >> 6, lane = threadIdx.x & 63;
    const int n = blockIdx.x * 4 + wid;
    if (n >= N_NODES) return;
    const int s = offs[n], e = offs[n + 1];
    const int m = e - s;

    float a00=0,a01=0,a02=0,a03=0,a04=0,a05=0,a06=0,a07=0;
    float a10=0,a11=0,a12=0,a13=0,a14=0,a15=0,a16=0,a17=0;
    float a20=0,a21=0,a22=0,a23=0,a24=0,a25=0,a26=0,a27=0;
    int k0 = 0, k1 = 0, k2 = 0;

    int pl = (lane < m) ? sorted[s + lane] : 0;
    const int mm = m < 64 ? m : 64;
    int i = 0;
    for (; i + 2 <= mm; i += 2) {                    // 2 independent gathers in flight
        int p0 = __shfl(pl, i);
        int p1 = __shfl(pl, i + 1);
        uint4 v0 = ((const uint4*)(xb + (size_t)(p0 & 0xffff) * D))[lane];
        uint4 v1 = ((const uint4*)(xb + (size_t)(p1 & 0xffff) * D))[lane];
        int r0 = p0 >> 16, r1 = p1 >> 16;
        ACC_EDGE(r0, v0);
        ACC_EDGE(r1, v1);
    }
    if (i < mm) {
        int p = __shfl(pl, i);
        uint4 v = ((const uint4*)(xb + (size_t)(p & 0xffff) * D))[lane];
        int r = p >> 16;
        ACC_EDGE(r, v);
    }
    for (int j = 64; j < m; ++j) {       // overflow path (essentially never taken)
        int p = sorted[s + j];
        uint4 v = ((const uint4*)(xb + (size_t)(p & 0xffff) * D))[lane];
        int r = p >> 16;
        ACC_EDGE(r, v);
    }

    const int rowid = noderow[n];
    // tiled write: lane holds k = slot*512 + lane*8 .. +7 of row `rowid`
    //   tile = (rowid>>4)*64 + slot*16 + (lane>>2)
    //   off  = ((lane&3)*16 + (rowid&15))*8
    short* base = A + (size_t)(rowid >> 4) * 64 * 512
                    + (size_t)(lane >> 2) * 512
                    + ((lane & 3) * 16 + (rowid & 15)) * 8;
    uint4 q;
    q.x = pack2(a00, a01); q.y = pack2(a02, a03); q.z = pack2(a04, a05); q.w = pack2(a06, a07);
    *(uint4*)(base + 0 * 16 * 512) = q;
    q.x = pack2(a10, a11); q.y = pack2(a12, a13); q.z = pack2(a14, a15); q.w = pack2(a16, a17);
    *(uint4*)(base + 1 * 16 * 512) = q;
    q.x = pack2(a20, a21); q.y = pack2(a22, a23); q.z = pack2(a24, a25); q.w = pack2(a26, a27);
    *(uint4*)(base + 2 * 16 * 512) = q;
    // self slot = xb[n]
    *(uint4*)(base + 3 * 16 * 512) = ((const uint4*)(xb + (size_t)n * D))[lane];

    if (lane == 0) {
        cnt[n] = k0;
        cnt[N_NODES + n] = k1;
        cnt[2 * N_NODES + n] = k2;
    }
}

// ---- GEMM: no LDS, no barriers; fragment-direct loads from tiled A/Bt ----
__global__ __launch_bounds__(256, 3) void gemm_bias_relu(
    const short* __restrict__ A, const short* __restrict__ Bt,
    float* __restrict__ out,
    const int* __restrict__ cnt, const float* __restrict__ b_rel,
    const float* __restrict__ b_self, const int* __restrict__ typeoff,
    const int* __restrict__ rowmap) {
    const int tid = threadIdx.x;
    const int lane = tid & 63;
    const int wid = tid >> 6;
    const int wm = wid >> 1, wn = wid & 1;
    const int lr = lane & 15, lk = lane >> 4;

    // bijective XCD-chunk swizzle: 640 blocks, 8 XCDs, 80/XCD; tn-siblings adjacent
    const int lin = blockIdx.x;
    const int mapped = (lin & 7) * 80 + (lin >> 3);
    const int tm = mapped >> 2;
    const int tn = mapped & 3;

    const int o1 = typeoff[1], o2 = typeoff[2], Mtot = typeoff[3];
    const int arow0 = tm * 128;
    if (arow0 >= Mtot) return;
    const int ttile = (arow0 >= o2) ? 2 : (arow0 >= o1) ? 1 : 0;
    const int tsel = ttile * 512;
    const int brow0 = tn * 128;

    // fragment base pointers (tiled layout: +k0*16 elems per K32 step)
    const short* aB[4];
    const short* bB[4];
#pragma unroll
    for (int m = 0; m < 4; ++m)
        aB[m] = A + (size_t)((arow0 >> 4) + wm * 4 + m) * 64 * 512 + lane * 8;
#pragma unroll
    for (int n = 0; n < 4; ++n)
        bB[n] = Bt + (size_t)((brow0 >> 4) + wn * 4 + n) * 96 * 512 + lane * 8;

    f32x4_t acc[4][4] = {};

    // rel region: k in [0, 1536)
#pragma unroll 2
    for (int k0 = 0; k0 < KREL; k0 += 32) {
        bf16x8_t af[4], bfr[4];
#pragma unroll
        for (int m = 0; m < 4; ++m) af[m] = *(const bf16x8_t*)(aB[m] + k0 * 16);
#pragma unroll
        for (int n = 0; n < 4; ++n) bfr[n] = *(const bf16x8_t*)(bB[n] + k0 * 16);
#pragma unroll
        for (int m = 0; m < 4; ++m)
#pragma unroll
            for (int n = 0; n < 4; ++n)
                acc[m][n] = __builtin_amdgcn_mfma_f32_16x16x32_bf16(af[m], bfr[n], acc[m][n], 0, 0, 0);
    }
    // self region: k in [1536, 2048); B offset by type-selected 512-chunk
#pragma unroll 2
    for (int k0 = KREL; k0 < KK; k0 += 32) {
        bf16x8_t af[4], bfr[4];
#pragma unroll
        for (int m = 0; m < 4; ++m) af[m] = *(const bf16x8_t*)(aB[m] + k0 * 16);
#pragma unroll
        for (int n = 0; n < 4; ++n) bfr[n] = *(const bf16x8_t*)(bB[n] + (k0 + tsel) * 16);
#pragma unroll
        for (int m = 0; m < 4; ++m)
#pragma unroll
            for (int n = 0; n < 4; ++n)
                acc[m][n] = __builtin_amdgcn_mfma_f32_16x16x32_bf16(af[m], bfr[n], acc[m][n], 0, 0, 0);
    }

#pragma unroll
    for (int m = 0; m < 4; ++m) {
#pragma unroll
        for (int q = 0; q < 4; ++q) {
            int rowg = arow0 + wm * 64 + m * 16 + lk * 4 + q;
            int node = rowmap[rowg];
            if (node < 0) continue;
            float c0 = (float)cnt[node];
            float c1 = (float)cnt[N_NODES + node];
            float c2 = (float)cnt[2 * N_NODES + node];
#pragma unroll
            for (int n = 0; n < 4; ++n) {
                int colg = tn * 128 + wn * 64 + n * 16 + lr;
                float v = acc[m][n][q];
                v += c0 * b_rel[colg] + c1 * b_rel[D + colg] + c2 * b_rel[2 * D + colg];
                v += b_self[tsel + colg];
                v = v > 0.f ? v : 0.f;
                out[(size_t)node * D + colg] = v;
            }
        }
    }
}

extern "C" void kernel_launch(void* const* d_in, const int* in_sizes, int n_in,
                              void* d_out, int out_size, void* d_ws, size_t ws_size,
                              hipStream_t stream) {
    const float* x      = (const float*)d_in[0];
    const float* W_rel  = (const float*)d_in[1];
    const float* b_rel  = (const float*)d_in[2];
    const float* W_self = (const float*)d_in[3];
    const float* b_self = (const float*)d_in[4];
    const int* esrc     = (const int*)d_in[5];
    const int* edst     = (const int*)d_in[6];
    const int* etyp     = (const int*)d_in[7];
    const int* ntyp     = (const int*)d_in[8];
    float* out = (float*)d_out;

    char* ws = (char*)d_ws;
    size_t o = 0;
    short* A       = (short*)(ws + o); o += (size_t)NROWS * KK * 2;      // 83,886,080 (tiled)
    short* Bt      = (short*)(ws + o); o += (size_t)D * 3072 * 2;        // 3,145,728 (tiled)
    short* xb      = (short*)(ws + o); o += (size_t)N_NODES * D * 2;     // 20,480,000
    int*   cnt     = (int*)(ws + o);   o += (size_t)3 * N_NODES * 4;     // 240,000
    int*   offs    = (int*)(ws + o);   o += 80032;
    int*   cur     = (int*)(ws + o);   o += 80000;
    int*   noderow = (int*)(ws + o);   o += 80000;
    int*   rowmap  = (int*)(ws + o);   o += (size_t)NROWS * 4;           // 81,920
    int*   sorted  = (int*)(ws + o);   o += 600000;
    // zero-region (memset): hist + tcnt + tcur + typeoff, contiguous 80048 B
    int*   hist    = (int*)(ws + o);   o += 80000;
    int*   tcnt    = (int*)(ws + o);   o += 16;
    int*   tcur    = (int*)(ws + o);   o += 16;
    int*   typeoff = (int*)(ws + o);   o += 16;

    hipMemsetAsync(hist, 0, 80048, stream);
    fused_prep<<<TB_BLOCKS + CX_BLOCKS + CNT_BLOCKS, 256, 0, stream>>>(
        W_rel, W_self, Bt, x, xb, edst, hist, ntyp, tcnt);
    scan_k<<<1, 1024, 0, stream>>>(hist, offs, cur, tcnt, typeoff, rowmap);
    assign_scatter_k<<<(N_EDGES + 255) / 256, 256, 0, stream>>>(
        ntyp, typeoff, tcur, noderow, rowmap, esrc, edst, etyp, cur, sorted);
    aggregate<<<(N_NODES + 3) / 4, 256, 0, stream>>>(xb, offs, sorted, noderow, A, cnt);
    gemm_bias_relu<<<NTILES_M * 4, 256, 0, stream>>>(A, Bt, out, cnt, b_rel, b_self,
                                                     typeoff, rowmap);
}

// Round 9
// 169.998 us; speedup vs baseline: 1.2706x; 1.2706x over previous
//
#include <hip/hip_runtime.h>
#include <hip/hip_bf16.h>

#define N_NODES 20000
#define N_EDGES 150000
#define D 512
#define KK 2048          // GEMM K: 3 rel slots (in A) + 1 self slot (from xb)
#define KREL 1536        // A row stride (3 rel slots only)
#define NROWS 20480
#define NTILES_M 320     // 64-row M tiles

typedef __attribute__((ext_vector_type(8))) short bf16x8_t;
typedef __attribute__((ext_vector_type(4))) float f32x4_t;

// ---- helpers ----
__device__ __forceinline__ unsigned short f2bf(float x) {
    unsigned u = __float_as_uint(x);
    unsigned r = u + 0x7fffu + ((u >> 16) & 1u);   // RNE
    return (unsigned short)(r >> 16);
}
__device__ __forceinline__ unsigned pack2(float a, float b) {
    return (unsigned)f2bf(a) | ((unsigned)f2bf(b) << 16);
}
__device__ __forceinline__ float bflo(unsigned u) { return __uint_as_float(u << 16); }
__device__ __forceinline__ float bfhi(unsigned u) { return __uint_as_float(u & 0xffff0000u); }

#define GLOAD16(g, l)                                                                   \
    __builtin_amdgcn_global_load_lds(                                                   \
        (const __attribute__((address_space(1))) unsigned*)(g),                         \
        (__attribute__((address_space(3))) unsigned*)(l), 16, 0, 0)

#define VMCNT(n) do { asm volatile("s_waitcnt vmcnt(" #n ")" ::: "memory");             \
                      __builtin_amdgcn_sched_barrier(0); } while (0)
#define BARS() do { __builtin_amdgcn_s_barrier();                                       \
                    __builtin_amdgcn_sched_barrier(0); } while (0)

// ---- fused prep: transpose_B (384 blocks) | conv_x (5000) | count (587) ----
#define TB_BLOCKS 384
#define CX_BLOCKS 5000
#define CNT_BLOCKS 587
__global__ __launch_bounds__(256) void fused_prep(
    const float* __restrict__ W_rel, const float* __restrict__ W_self,
    short* __restrict__ Bt,
    const float* __restrict__ x, short* __restrict__ xb,
    const int* __restrict__ edst, int* __restrict__ hist,
    const int* __restrict__ ntype, int* __restrict__ tcnt) {
    __shared__ float tile[64][65];
    const int b = blockIdx.x;
    if (b < TB_BLOCKS) {
        const int z = b >> 6;                         // 0..5
        const int rem = b & 63;
        const int e0 = (rem & 7) * 64, d0 = (rem >> 3) * 64;
        const float* src = (z < 3) ? (W_rel + (size_t)z * D * D)
                                   : (W_self + (size_t)(z - 3) * D * D);
        const int cbase = (z < 3) ? z * 512 : KREL + (z - 3) * 512;
        const int tx = threadIdx.x & 63, ty = threadIdx.x >> 6;
#pragma unroll
        for (int j = 0; j < 16; ++j) {
            int dl = ty * 16 + j;
            tile[dl][tx] = src[(size_t)(d0 + dl) * D + e0 + tx];
        }
        __syncthreads();
#pragma unroll
        for (int j = 0; j < 16; ++j) {
            int el = ty * 16 + j;
            Bt[(size_t)(e0 + el) * 3072 + cbase + d0 + tx] = (short)f2bf(tile[tx][el]);
        }
    } else if (b < TB_BLOCKS + CX_BLOCKS) {
        int idx = (b - TB_BLOCKS) * 256 + threadIdx.x;   // < 1,280,000
        const float4* s = (const float4*)x + (size_t)idx * 2;
        float4 a = s[0], bb = s[1];
        uint4 pk;
        pk.x = pack2(a.x, a.y);  pk.y = pack2(a.z, a.w);
        pk.z = pack2(bb.x, bb.y); pk.w = pack2(bb.z, bb.w);
        ((uint4*)xb)[idx] = pk;
    } else {
        int i = (b - TB_BLOCKS - CX_BLOCKS) * 256 + threadIdx.x;
        if (i < N_EDGES) atomicAdd(&hist[edst[i]], 1);
        int lane = threadIdx.x & 63;
        int t = (i < N_NODES) ? ntype[i] : 3;
        unsigned long long m0 = __ballot(t == 0), m1 = __ballot(t == 1), m2 = __ballot(t == 2);
        if (lane == 0) {
            if (m0) atomicAdd(&tcnt[0], __popcll(m0));
            if (m1) atomicAdd(&tcnt[1], __popcll(m1));
            if (m2) atomicAdd(&tcnt[2], __popcll(m2));
        }
    }
}

// ---- scan of 20000 edge-bins -> offs/cur; typeoff; rowmap padding marks ----
__global__ __launch_bounds__(1024) void scan_k(const int* __restrict__ hist,
                                               int* __restrict__ offs,
                                               int* __restrict__ cur,
                                               const int* __restrict__ tcnt,
                                               int* __restrict__ typeoff,
                                               int* __restrict__ rowmap) {
    __shared__ int part[1024];
    const int t = threadIdx.x;
    const int base = t * 20;
    int local[20];
    int sum = 0;
#pragma unroll
    for (int i = 0; i < 20; ++i) {
        int b = base + i;
        int v = (b < N_NODES) ? hist[b] : 0;
        local[i] = sum;
        sum += v;
    }
    part[t] = sum;
    __syncthreads();
    for (int off = 1; off < 1024; off <<= 1) {
        int v = part[t];
        int u = (t >= off) ? part[t - off] : 0;
        __syncthreads();
        part[t] = v + u;
        __syncthreads();
    }
    int tbase = (t > 0) ? part[t - 1] : 0;
#pragma unroll
    for (int i = 0; i < 20; ++i) {
        int b = base + i;
        if (b < N_NODES) {
            int o = tbase + local[i];
            offs[b] = o;
            cur[b] = o;
        }
    }
    if (t == 1023) offs[N_NODES] = part[1023];

    int c0 = tcnt[0], c1 = tcnt[1], c2 = tcnt[2];
    int o1 = (c0 + 127) & ~127;
    int o2 = o1 + ((c1 + 127) & ~127);
    int o3 = o2 + ((c2 + 127) & ~127);
    if (t == 0) { typeoff[0] = 0; typeoff[1] = o1; typeoff[2] = o2; typeoff[3] = o3; }
    int p0 = o1 - c0, p1 = o2 - o1 - c1, p2 = o3 - o2 - c2;
    if (t < p0) rowmap[c0 + t] = -1;
    else if (t < p0 + p1) rowmap[o1 + c1 + (t - p0)] = -1;
    else if (t - p0 - p1 < p2) rowmap[o2 + c2 + (t - p0 - p1)] = -1;
}

// ---- node->row assignment (type-grouped) + edge-id scatter (fused) ----
__global__ __launch_bounds__(256) void assign_scatter_k(
    const int* __restrict__ ntype, const int* __restrict__ typeoff,
    int* __restrict__ tcur, int* __restrict__ noderow, int* __restrict__ rowmap,
    const int* __restrict__ esrc, const int* __restrict__ edst,
    const int* __restrict__ etyp, int* __restrict__ cur, int* __restrict__ sorted) {
    int i = blockIdx.x * 256 + threadIdx.x;
    int lane = threadIdx.x & 63;
    bool valid = i < N_NODES;
    int t = valid ? ntype[i] : 3;
    unsigned long long m0 = __ballot(t == 0), m1 = __ballot(t == 1), m2 = __ballot(t == 2);
    unsigned long long below = (lane == 0) ? 0ull : (~0ull >> (64 - lane));
    int b0 = 0, b1 = 0, b2 = 0;
    if (lane == 0) {
        if (m0) b0 = atomicAdd(&tcur[0], __popcll(m0));
        if (m1) b1 = atomicAdd(&tcur[1], __popcll(m1));
        if (m2) b2 = atomicAdd(&tcur[2], __popcll(m2));
    }
    b0 = __shfl(b0, 0); b1 = __shfl(b1, 0); b2 = __shfl(b2, 0);
    if (valid) {
        unsigned long long mk = (t == 0) ? m0 : (t == 1) ? m1 : m2;
        int bs = (t == 0) ? b0 : (t == 1) ? b1 : b2;
        int row = typeoff[t] + bs + __popcll(mk & below);
        noderow[i] = row;
        rowmap[row] = i;
    }
    if (i < N_EDGES) {
        int dst = edst[i];
        int pos = atomicAdd(&cur[dst], 1);
        sorted[pos] = esrc[i] | (etyp[i] << 16);
    }
}

// ---- aggregate: one wave per dst node; 4 gathers in flight; linear A writes ----
#define ACC_EDGE(r, v) {                                                              \
    float f0 = bflo(v.x), f1 = bfhi(v.x), f2 = bflo(v.y), f3 = bfhi(v.y);             \
    float f4 = bflo(v.z), f5 = bfhi(v.z), f6 = bflo(v.w), f7 = bfhi(v.w);             \
    if (r == 0) { a00+=f0;a01+=f1;a02+=f2;a03+=f3;a04+=f4;a05+=f5;a06+=f6;a07+=f7; k0++; } \
    else if (r == 1) { a10+=f0;a11+=f1;a12+=f2;a13+=f3;a14+=f4;a15+=f5;a16+=f6;a17+=f7; k1++; } \
    else { a20+=f0;a21+=f1;a22+=f2;a23+=f3;a24+=f4;a25+=f5;a26+=f6;a27+=f7; k2++; }   \
}
__global__ __launch_bounds__(256) void aggregate(const short* __restrict__ xb,
                                                 const int* __restrict__ offs,
                                                 const int* __restrict__ sorted,
                                                 const int* __restrict__ noderow,
                                                 short* __restrict__ A,
                                                 int* __restrict__ cnt) {
    const int wid = threadIdx.x >> 6, lane = threadIdx.x & 63;
    const int n = blockIdx.x * 4 + wid;
    if (n >= N_NODES) return;
    const int s = offs[n], e = offs[n + 1];
    const int m = e - s;

    float a00=0,a01=0,a02=0,a03=0,a04=0,a05=0,a06=0,a07=0;
    float a10=0,a11=0,a12=0,a13=0,a14=0,a15=0,a16=0,a17=0;
    float a20=0,a21=0,a22=0,a23=0,a24=0,a25=0,a26=0,a27=0;
    int k0 = 0, k1 = 0, k2 = 0;

    int pl = (lane < m) ? sorted[s + lane] : 0;
    const int mm = m < 64 ? m : 64;
    int i = 0;
    for (; i + 4 <= mm; i += 4) {                    // 4 independent gathers in flight
        int p0 = __shfl(pl, i);
        int p1 = __shfl(pl, i + 1);
        int p2 = __shfl(pl, i + 2);
        int p3 = __shfl(pl, i + 3);
        uint4 v0 = ((const uint4*)(xb + (size_t)(p0 & 0xffff) * D))[lane];
        uint4 v1 = ((const uint4*)(xb + (size_t)(p1 & 0xffff) * D))[lane];
        uint4 v2 = ((const uint4*)(xb + (size_t)(p2 & 0xffff) * D))[lane];
        uint4 v3 = ((const uint4*)(xb + (size_t)(p3 & 0xffff) * D))[lane];
        int r0 = p0 >> 16, r1 = p1 >> 16, r2 = p2 >> 16, r3 = p3 >> 16;
        ACC_EDGE(r0, v0);
        ACC_EDGE(r1, v1);
        ACC_EDGE(r2, v2);
        ACC_EDGE(r3, v3);
    }
    for (; i < mm; ++i) {
        int p = __shfl(pl, i);
        uint4 v = ((const uint4*)(xb + (size_t)(p & 0xffff) * D))[lane];
        int r = p >> 16;
        ACC_EDGE(r, v);
    }
    for (int j = 64; j < m; ++j) {       // overflow path (essentially never taken)
        int p = sorted[s + j];
        uint4 v = ((const uint4*)(xb + (size_t)(p & 0xffff) * D))[lane];
        int r = p >> 16;
        ACC_EDGE(r, v);
    }

    const int rowid = noderow[n];
    short* row = A + (size_t)rowid * KREL;
    uint4 q;
    q.x = pack2(a00, a01); q.y = pack2(a02, a03); q.z = pack2(a04, a05); q.w = pack2(a06, a07);
    *(uint4*)(row + 0 * D + lane * 8) = q;
    q.x = pack2(a10, a11); q.y = pack2(a12, a13); q.z = pack2(a14, a15); q.w = pack2(a16, a17);
    *(uint4*)(row + 1 * D + lane * 8) = q;
    q.x = pack2(a20, a21); q.y = pack2(a22, a23); q.z = pack2(a24, a25); q.w = pack2(a26, a27);
    *(uint4*)(row + 2 * D + lane * 8) = q;

    if (lane == 0) {
        cnt[n] = k0;
        cnt[N_NODES + n] = k1;
        cnt[2 * N_NODES + n] = k2;
    }
}

// ---- GEMM: 64x128 tile, BK=64, dbuf (48KB) + counted vmcnt, 3 blocks/CU ----
__global__ __launch_bounds__(256, 3) void gemm_bias_relu(
    const short* __restrict__ A, const short* __restrict__ Bt,
    const short* __restrict__ xb, float* __restrict__ out,
    const int* __restrict__ cnt, const float* __restrict__ b_rel,
    const float* __restrict__ b_self, const int* __restrict__ typeoff,
    const int* __restrict__ rowmap) {
    __shared__ short lA[2][64 * 64];
    __shared__ short lB[2][128 * 64];
    const int tid = threadIdx.x;
    const int lane = tid & 63;
    const int wid = tid >> 6;
    const int wm = wid >> 1, wn = wid & 1;
    const int lr = lane & 15, lk = lane >> 4;

    // bijective XCD-chunk swizzle: 1280 blocks, 8 XCDs, 160/XCD; tn-siblings adjacent
    const int lin = blockIdx.x;
    const int mapped = (lin & 7) * 160 + (lin >> 3);
    const int tm = mapped >> 2;
    const int tn = mapped & 3;

    const int o1 = typeoff[1], o2 = typeoff[2], Mtot = typeoff[3];
    const int arow0 = tm * 64;
    if (arow0 >= Mtot) return;
    const int ttile = (arow0 >= o2) ? 2 : (arow0 >= o1) ? 1 : 0;
    const int tsel = ttile * 512;
    const int brow0 = tn * 128;

    // staging precompute: 2 A-frags + 4 B-frags per thread, source-side swizzle
    const int rowA0 = tid >> 3;
    const int rowA1 = rowA0 + 32;
    const int frA0 = (tid & 7) ^ (rowA0 & 7);
    const int frA1 = (tid & 7) ^ (rowA1 & 7);
    int nA0 = rowmap[arow0 + rowA0]; if (nA0 < 0) nA0 = 0;
    int nA1 = rowmap[arow0 + rowA1]; if (nA1 < 0) nA1 = 0;
    const short* aA0 = A + (size_t)(arow0 + rowA0) * KREL + frA0 * 8;
    const short* aA1 = A + (size_t)(arow0 + rowA1) * KREL + frA1 * 8;
    const short* xA0 = xb + (size_t)nA0 * D + frA0 * 8;
    const short* xA1 = xb + (size_t)nA1 * D + frA1 * 8;
    const short* bPtr[4];
#pragma unroll
    for (int rr = 0; rr < 4; ++rr) {
        int p = rr * 256 + tid;
        int row = p >> 3;
        int fr = (p & 7) ^ (row & 7);
        bPtr[rr] = Bt + (size_t)(brow0 + row) * 3072 + fr * 8;
    }
    char* const ldsAc = (char*)&lA[0][0];
    char* const ldsBc = (char*)&lB[0][0];

#define STAGE(kt, buf) {                                                              \
    const int k0s = (kt) * 64;                                                        \
    if (k0s < KREL) {                                                                 \
        GLOAD16(aA0 + k0s, ldsAc + (buf) * 8192 + tid * 16);                          \
        GLOAD16(aA1 + k0s, ldsAc + (buf) * 8192 + (256 + tid) * 16);                  \
    } else {                                                                          \
        GLOAD16(xA0 + (k0s - KREL), ldsAc + (buf) * 8192 + tid * 16);                 \
        GLOAD16(xA1 + (k0s - KREL), ldsAc + (buf) * 8192 + (256 + tid) * 16);         \
    }                                                                                 \
    const int bk0s = k0s + (k0s >= KREL ? tsel : 0);                                  \
    _Pragma("unroll")                                                                 \
    for (int rr = 0; rr < 4; ++rr)                                                    \
        GLOAD16(bPtr[rr] + bk0s, ldsBc + (buf) * 16384 + (rr * 256 + tid) * 16);      \
}

#define COMPUTE(buf) {                                                                \
    _Pragma("unroll")                                                                 \
    for (int ks = 0; ks < 2; ++ks) {                                                  \
        bf16x8_t af[2], bfr[4];                                                       \
        _Pragma("unroll")                                                             \
        for (int m = 0; m < 2; ++m) {                                                 \
            int row_l = wm * 32 + m * 16 + lr;                                        \
            int pos = (row_l << 3) + ((ks * 4 + lk) ^ (row_l & 7));                   \
            af[m] = *(const bf16x8_t*)&lA[buf][pos << 3];                             \
        }                                                                             \
        _Pragma("unroll")                                                             \
        for (int n = 0; n < 4; ++n) {                                                 \
            int row_l = wn * 64 + n * 16 + lr;                                        \
            int pos = (row_l << 3) + ((ks * 4 + lk) ^ (row_l & 7));                   \
            bfr[n] = *(const bf16x8_t*)&lB[buf][pos << 3];                            \
        }                                                                             \
        __builtin_amdgcn_s_setprio(1);                                                \
        _Pragma("unroll")                                                             \
        for (int m = 0; m < 2; ++m)                                                   \
            _Pragma("unroll")                                                         \
            for (int n = 0; n < 4; ++n)                                               \
                acc[m][n] = __builtin_amdgcn_mfma_f32_16x16x32_bf16(                  \
                    af[m], bfr[n], acc[m][n], 0, 0, 0);                               \
        __builtin_amdgcn_s_setprio(0);                                                \
    }                                                                                 \
}

    f32x4_t acc[2][4] = {};

    STAGE(0, 0);
#pragma unroll 1
    for (int kt = 0; kt < 32; kt += 2) {
        STAGE(kt + 1, 1);         // kt+1 <= 31 always
        VMCNT(6);                 // tile kt landed (6 newest = tile kt+1 in flight)
        BARS();
        COMPUTE(0);
        BARS();                   // all waves done reading buf0
        if (kt + 2 < 32) {
            STAGE(kt + 2, 0);
            VMCNT(6);             // tile kt+1 landed
        } else {
            VMCNT(0);             // epilogue drain
        }
        BARS();
        COMPUTE(1);
        BARS();                   // buf1 safe to overwrite next iteration
    }

#pragma unroll
    for (int m = 0; m < 2; ++m) {
#pragma unroll
        for (int q = 0; q < 4; ++q) {
            int rowg = arow0 + wm * 32 + m * 16 + lk * 4 + q;
            int node = rowmap[rowg];
            if (node < 0) continue;
            float c0 = (float)cnt[node];
            float c1 = (float)cnt[N_NODES + node];
            float c2 = (float)cnt[2 * N_NODES + node];
#pragma unroll
            for (int n = 0; n < 4; ++n) {
                int colg = tn * 128 + wn * 64 + n * 16 + lr;
                float v = acc[m][n][q];
                v += c0 * b_rel[colg] + c1 * b_rel[D + colg] + c2 * b_rel[2 * D + colg];
                v += b_self[tsel + colg];
                v = v > 0.f ? v : 0.f;
                out[(size_t)node * D + colg] = v;
            }
        }
    }
}

extern "C" void kernel_launch(void* const* d_in, const int* in_sizes, int n_in,
                              void* d_out, int out_size, void* d_ws, size_t ws_size,
                              hipStream_t stream) {
    const float* x      = (const float*)d_in[0];
    const float* W_rel  = (const float*)d_in[1];
    const float* b_rel  = (const float*)d_in[2];
    const float* W_self = (const float*)d_in[3];
    const float* b_self = (const float*)d_in[4];
    const int* esrc     = (const int*)d_in[5];
    const int* edst     = (const int*)d_in[6];
    const int* etyp     = (const int*)d_in[7];
    const int* ntyp     = (const int*)d_in[8];
    float* out = (float*)d_out;

    char* ws = (char*)d_ws;
    size_t o = 0;
    short* A       = (short*)(ws + o); o += (size_t)NROWS * KREL * 2;    // 62,914,560
    short* Bt      = (short*)(ws + o); o += (size_t)D * 3072 * 2;        // 3,145,728
    short* xb      = (short*)(ws + o); o += (size_t)N_NODES * D * 2;     // 20,480,000
    int*   cnt     = (int*)(ws + o);   o += (size_t)3 * N_NODES * 4;     // 240,000
    int*   offs    = (int*)(ws + o);   o += 80032;
    int*   cur     = (int*)(ws + o);   o += 80000;
    int*   noderow = (int*)(ws + o);   o += 80000;
    int*   rowmap  = (int*)(ws + o);   o += (size_t)NROWS * 4;           // 81,920
    int*   sorted  = (int*)(ws + o);   o += 600000;
    // zero-region (memset): hist + tcnt + tcur + typeoff, contiguous 80048 B
    int*   hist    = (int*)(ws + o);   o += 80000;
    int*   tcnt    = (int*)(ws + o);   o += 16;
    int*   tcur    = (int*)(ws + o);   o += 16;
    int*   typeoff = (int*)(ws + o);   o += 16;

    hipMemsetAsync(hist, 0, 80048, stream);
    fused_prep<<<TB_BLOCKS + CX_BLOCKS + CNT_BLOCKS, 256, 0, stream>>>(
        W_rel, W_self, Bt, x, xb, edst, hist, ntyp, tcnt);
    scan_k<<<1, 1024, 0, stream>>>(hist, offs, cur, tcnt, typeoff, rowmap);
    assign_scatter_k<<<(N_EDGES + 255) / 256, 256, 0, stream>>>(
        ntyp, typeoff, tcur, noderow, rowmap, esrc, edst, etyp, cur, sorted);
    aggregate<<<(N_NODES + 3) / 4, 256, 0, stream>>>(xb, offs, sorted, noderow, A, cnt);
    gemm_bias_relu<<<NTILES_M * 4, 256, 0, stream>>>(A, Bt, xb, out, cnt, b_rel, b_self,
                                                     typeoff, rowmap);
}